// Round 1
// baseline (462.470 us; speedup 1.0000x reference)
//
#include <hip/hip_runtime.h>
#include <hip/hip_bf16.h>

#define NN 10000
#define NE 100000

__device__ __forceinline__ float bcast(float v, int k) {
  return __int_as_float(__builtin_amdgcn_readlane(__float_as_int(v), k));
}
__device__ __forceinline__ unsigned int enc_f(float f) {
  unsigned int u = __float_as_uint(f);
  return (u & 0x80000000u) ? ~u : (u | 0x80000000u);
}
__device__ __forceinline__ float dec_f(unsigned int u) {
  return __uint_as_float((u & 0x80000000u) ? (u & 0x7fffffffu) : ~u);
}
__device__ __forceinline__ float silu_f(float x) {
  return x / (1.0f + __expf(-x));
}

// ---------------- prep: Q[c,h] = sum_dv W_val[c,h*16+dv]*W_out[h*16+dv]; WmsgT = W_msg^T
__global__ void prep_kernel(const float* __restrict__ W_msg,
                            const float* __restrict__ W_val,
                            const float* __restrict__ W_out,
                            float* __restrict__ Q, float* __restrict__ WmsgT) {
  int i = blockIdx.x * blockDim.x + threadIdx.x;
  if (i < 1024) {
    int c = i >> 3, h = i & 7;
    float s = 0.0f;
#pragma unroll
    for (int dv = 0; dv < 16; ++dv)
      s += W_val[c * 128 + h * 16 + dv] * W_out[h * 16 + dv];
    Q[c * 8 + h] = s;
  }
  if (i < 16384) {
    int c = i >> 7, k = i & 127;
    WmsgT[c * 128 + k] = W_msg[k * 128 + c];
  }
}

// ---------------- pass1: gate (bf16 to ws), logits, segment-max(m_enc)
__global__ __launch_bounds__(256) void pass1_kernel(
    const float* __restrict__ nb, const int* __restrict__ zn,
    const float* __restrict__ dist, const int* __restrict__ ei,
    const float* __restrict__ wig, const float* __restrict__ aemb,
    const float* __restrict__ W_rbf, const float* __restrict__ W_gate,
    const float* __restrict__ W_msg, const float* __restrict__ alpha,
    float* __restrict__ logits, unsigned int* __restrict__ m_enc,
    __hip_bfloat16* __restrict__ gate_ws) {
  const int lane = threadIdx.x & 63;
  const int wid = threadIdx.x >> 6;
  const int e0 = (blockIdx.x * 4 + wid) * 4;  // 4 edges per wave; E divisible by 16

  int src[4], dst[4];
  float dd[4];
#pragma unroll
  for (int e = 0; e < 4; ++e) {
    src[e] = ei[e0 + e];
    dst[e] = ei[NE + e0 + e];
    dd[e] = dist[e0 + e];
  }

  // rbf[k] = exp(-8192*(d - k/127)^2); lane holds k=lane and k=lane+64
  const float cc0 = (float)lane * (1.0f / 127.0f);
  const float cc1 = (float)(lane + 64) * (1.0f / 127.0f);
  float r0[4], r1[4];
#pragma unroll
  for (int e = 0; e < 4; ++e) {
    float t0 = dd[e] - cc0, t1 = dd[e] - cc1;
    r0[e] = __expf(-8192.0f * t0 * t0);
    r1[e] = __expf(-8192.0f * t1 * t1);
  }

  // es = silu(rbf @ W_rbf + aemb[z_src] + aemb[z_dst]) ; c = lane
  float acc[4];
#pragma unroll
  for (int e = 0; e < 4; ++e)
    acc[e] = aemb[zn[src[e]] * 64 + lane] + aemb[zn[dst[e]] * 64 + lane];
#pragma unroll 8
  for (int k = 0; k < 64; ++k) {
    float w0 = W_rbf[k * 64 + lane];
    float w1 = W_rbf[(k + 64) * 64 + lane];
#pragma unroll
    for (int e = 0; e < 4; ++e)
      acc[e] += bcast(r0[e], k) * w0 + bcast(r1[e], k) * w1;
  }
  float es[4];
#pragma unroll
  for (int e = 0; e < 4; ++e) es[e] = silu_f(acc[e]);

  // gate = silu(es @ W_gate) ; c = lane and lane+64
  float g0[4] = {0, 0, 0, 0}, g1[4] = {0, 0, 0, 0};
#pragma unroll 8
  for (int k = 0; k < 64; ++k) {
    float w0 = W_gate[k * 128 + lane];
    float w1 = W_gate[k * 128 + 64 + lane];
#pragma unroll
    for (int e = 0; e < 4; ++e) {
      float s = bcast(es[e], k);
      g0[e] += s * w0;
      g1[e] += s * w1;
    }
  }
#pragma unroll
  for (int e = 0; e < 4; ++e) {
    g0[e] = silu_f(g0[e]);
    g1[e] = silu_f(g1[e]);
    gate_ws[(size_t)(e0 + e) * 128 + lane] = __float2bfloat16(g0[e]);
    gate_ws[(size_t)(e0 + e) * 128 + 64 + lane] = __float2bfloat16(g1[e]);
  }

  // x0 = wigner row0 applied to nb[src], nb[dst] ; c = lane
  float xs[4] = {0, 0, 0, 0}, xt[4] = {0, 0, 0, 0};
#pragma unroll
  for (int j = 0; j < 9; ++j) {
#pragma unroll
    for (int e = 0; e < 4; ++e) {
      float wj = wig[(size_t)(e0 + e) * 81 + j];
      xs[e] += wj * nb[(size_t)src[e] * 576 + j * 64 + lane];
      xt[e] += wj * nb[(size_t)dst[e] * 576 + j * 64 + lane];
    }
  }

  // msg0 = (concat(xs,xt) @ W_msg) ; c = lane and lane+64
  float m0[4] = {0, 0, 0, 0}, m1[4] = {0, 0, 0, 0};
#pragma unroll 8
  for (int k = 0; k < 64; ++k) {
    float w00 = W_msg[k * 128 + lane];
    float w01 = W_msg[k * 128 + 64 + lane];
    float w10 = W_msg[(k + 64) * 128 + lane];
    float w11 = W_msg[(k + 64) * 128 + 64 + lane];
#pragma unroll
    for (int e = 0; e < 4; ++e) {
      float a0 = bcast(xs[e], k);
      float a1 = bcast(xt[e], k);
      m0[e] += a0 * w00 + a1 * w10;
      m1[e] += a0 * w01 + a1 * w11;
    }
  }

  // logits[h] = sum_d lrelu(msg0*gate)[h*16+d] * alpha[h*16+d]
  const float al0 = alpha[lane], al1 = alpha[64 + lane];
#pragma unroll
  for (int e = 0; e < 4; ++e) {
    float a0 = m0[e] * g0[e]; a0 = a0 > 0.0f ? a0 : 0.2f * a0;
    float a1 = m1[e] * g1[e]; a1 = a1 > 0.0f ? a1 : 0.2f * a1;
    float p0 = a0 * al0;
    float p1 = a1 * al1;
#pragma unroll
    for (int off = 1; off < 16; off <<= 1) {
      p0 += __shfl_xor(p0, off);
      p1 += __shfl_xor(p1, off);
    }
    if ((lane & 15) == 0) {
      int h0 = lane >> 4;  // 0..3 ; p0 -> h0, p1 -> h0+4
      logits[(size_t)(e0 + e) * 8 + h0] = p0;
      logits[(size_t)(e0 + e) * 8 + 4 + h0] = p1;
      atomicMax(&m_enc[dst[e] * 8 + h0], enc_f(p0));
      atomicMax(&m_enc[dst[e] * 8 + 4 + h0], enc_f(p1));
    }
  }
}

// ---------------- pass2: den[n,h] += exp(logit - m[n,h])
__global__ void pass2_kernel(const float* __restrict__ logits,
                             const int* __restrict__ ei,
                             const unsigned int* __restrict__ m_enc,
                             float* __restrict__ den) {
  int i = blockIdx.x * blockDim.x + threadIdx.x;
  if (i >= NE * 8) return;
  int e = i >> 3, h = i & 7;
  int dn = ei[NE + e];
  float mm = dec_f(m_enc[dn * 8 + h]);
  atomicAdd(&den[dn * 8 + h], __expf(logits[i] - mm));
}

// ---------------- pass3: folded message/value/force computation
__global__ __launch_bounds__(256) void pass3_kernel(
    const float* __restrict__ nb, const int* __restrict__ ei,
    const float* __restrict__ wig, const float* __restrict__ logits,
    const unsigned int* __restrict__ m_enc, const float* __restrict__ den,
    const __hip_bfloat16* __restrict__ gate_ws, const float* __restrict__ Q,
    const float* __restrict__ WmsgT, float* __restrict__ out) {
  const int lane = threadIdx.x & 63;
  const int wid = threadIdx.x >> 6;
  const int e0 = (blockIdx.x * 4 + wid) * 4;

  int src[4], dst[4];
#pragma unroll
  for (int e = 0; e < 4; ++e) {
    src[e] = ei[e0 + e];
    dst[e] = ei[NE + e0 + e];
  }

  // attn for (e,h) on lanes 0..31 : e = lane>>3, h = lane&7
  float attn_v = 0.0f;
  if (lane < 32) {
    int e = lane >> 3, h = lane & 7;
    int dn = ei[NE + e0 + e];
    float l = logits[(size_t)(e0 + e) * 8 + h];
    float mm = dec_f(m_enc[dn * 8 + h]);
    float dv = den[dn * 8 + h];
    attn_v = __expf(l - mm) / (dv + 1e-9f);
  }

  float g0[4], g1[4];
#pragma unroll
  for (int e = 0; e < 4; ++e) {
    g0[e] = __bfloat162float(gate_ws[(size_t)(e0 + e) * 128 + lane]);
    g1[e] = __bfloat162float(gate_ws[(size_t)(e0 + e) * 128 + 64 + lane]);
  }

  // wv[c] = sum_h Q[c,h]*attn[h] ; c = lane, lane+64
  float wv0[4] = {0, 0, 0, 0}, wv1[4] = {0, 0, 0, 0};
#pragma unroll
  for (int h = 0; h < 8; ++h) {
    float q0 = Q[lane * 8 + h];
    float q1 = Q[(lane + 64) * 8 + h];
#pragma unroll
    for (int e = 0; e < 4; ++e) {
      float a = bcast(attn_v, e * 8 + h);
      wv0[e] += q0 * a;
      wv1[e] += q1 * a;
    }
  }
  float u0[4], u1[4];
#pragma unroll
  for (int e = 0; e < 4; ++e) {
    u0[e] = g0[e] * wv0[e];
    u1[e] = g1[e] * wv1[e];
  }

  // t[k] = sum_c W_msg[k,c]*u[c] = sum_c WmsgT[c,k]*u[c] ; k = lane, lane+64
  float t0[4] = {0, 0, 0, 0}, t1[4] = {0, 0, 0, 0};
#pragma unroll 8
  for (int c = 0; c < 64; ++c) {
    float w00 = WmsgT[c * 128 + lane];
    float w01 = WmsgT[c * 128 + 64 + lane];
    float w10 = WmsgT[(c + 64) * 128 + lane];
    float w11 = WmsgT[(c + 64) * 128 + 64 + lane];
#pragma unroll
    for (int e = 0; e < 4; ++e) {
      float a0 = bcast(u0[e], c);
      float a1 = bcast(u1[e], c);
      t0[e] += a0 * w00 + a1 * w10;
      t1[e] += a0 * w01 + a1 * w11;
    }
  }

  // d[j'] = nb_src[j']·t_s + nb_dst[j']·t_t ; s[j] = wig[j,:]·d ; f_i = sum_j wig[j,i]*s[j]
#pragma unroll
  for (int e = 0; e < 4; ++e) {
    const float* ps = nb + (size_t)src[e] * 576 + lane;
    const float* pt = nb + (size_t)dst[e] * 576 + lane;
    float dj[9];
#pragma unroll
    for (int j = 0; j < 9; ++j) {
      float p = ps[j * 64] * t0[e] + pt[j * 64] * t1[e];
#pragma unroll
      for (int off = 32; off >= 1; off >>= 1) p += __shfl_xor(p, off);
      dj[j] = p;
    }
    const float* we = wig + (size_t)(e0 + e) * 81;
    float s_j = 0.0f;
    if (lane < 9) {
#pragma unroll
      for (int jp = 0; jp < 9; ++jp) s_j += we[lane * 9 + jp] * dj[jp];
    }
    if (lane >= 1 && lane <= 3) {
      float f = 0.0f;
#pragma unroll
      for (int j = 0; j < 9; ++j) f += bcast(s_j, j) * we[j * 9 + lane];
      atomicAdd(&out[dst[e] * 3 + (lane - 1)], f);
    }
  }
}

extern "C" void kernel_launch(void* const* d_in, const int* in_sizes, int n_in,
                              void* d_out, int out_size, void* d_ws, size_t ws_size,
                              hipStream_t stream) {
  const float* nb = (const float*)d_in[0];
  const int* zn = (const int*)d_in[1];
  const float* dist = (const float*)d_in[2];
  const int* ei = (const int*)d_in[3];
  const float* wig = (const float*)d_in[4];
  const float* aemb = (const float*)d_in[5];
  const float* W_rbf = (const float*)d_in[6];
  const float* W_gate = (const float*)d_in[7];
  const float* W_msg = (const float*)d_in[8];
  const float* alpha = (const float*)d_in[9];
  const float* W_val = (const float*)d_in[10];
  const float* W_out = (const float*)d_in[11];
  float* out = (float*)d_out;

  // workspace layout (~30 MB)
  char* p = (char*)d_ws;
  float* Q = (float*)p;               p += 1024 * 4;
  float* WmsgT = (float*)p;           p += 16384 * 4;
  unsigned int* m_enc = (unsigned int*)p; p += (size_t)NN * 8 * 4;
  float* den = (float*)p;             p += (size_t)NN * 8 * 4;
  float* logits = (float*)p;          p += (size_t)NE * 8 * 4;
  __hip_bfloat16* gate_ws = (__hip_bfloat16*)p;

  hipMemsetAsync(d_out, 0, (size_t)NN * 3 * 4, stream);
  hipMemsetAsync(m_enc, 0, (size_t)NN * 8 * 4, stream);
  hipMemsetAsync(den, 0, (size_t)NN * 8 * 4, stream);

  prep_kernel<<<64, 256, 0, stream>>>(W_msg, W_val, W_out, Q, WmsgT);
  pass1_kernel<<<NE / 16, 256, 0, stream>>>(nb, zn, dist, ei, wig, aemb, W_rbf,
                                            W_gate, W_msg, alpha, logits, m_enc,
                                            gate_ws);
  pass2_kernel<<<(NE * 8) / 256, 256, 0, stream>>>(logits, ei, m_enc, den);
  pass3_kernel<<<NE / 16, 256, 0, stream>>>(nb, ei, wig, logits, m_enc, den,
                                            gate_ws, Q, WmsgT, out);
}

// Round 2
// 356.197 us; speedup vs baseline: 1.2984x; 1.2984x over previous
//
#include <hip/hip_runtime.h>
#include <hip/hip_bf16.h>

#define NN 10000
#define NE 100000

typedef __attribute__((ext_vector_type(8))) short short8v;
typedef __attribute__((ext_vector_type(4))) float float4v;

__device__ __forceinline__ float bcast(float v, int k) {
  return __int_as_float(__builtin_amdgcn_readlane(__float_as_int(v), k));
}
__device__ __forceinline__ unsigned int enc_f(float f) {
  unsigned int u = __float_as_uint(f);
  return (u & 0x80000000u) ? ~u : (u | 0x80000000u);
}
__device__ __forceinline__ float dec_f(unsigned int u) {
  return __uint_as_float((u & 0x80000000u) ? (u & 0x7fffffffu) : ~u);
}
__device__ __forceinline__ float silu_f(float x) {
  return x / (1.0f + __expf(-x));
}
// fp32 -> bf16 hi/lo split: x ~= hi + lo with ~2^-16 relative error.
__device__ __forceinline__ void f32_hilo(float x, short& h, short& l) {
  __hip_bfloat16 bh = __float2bfloat16(x);
  float r = x - __bfloat162float(bh);
  __hip_bfloat16 bl = __float2bfloat16(r);
  h = __builtin_bit_cast(short, bh);
  l = __builtin_bit_cast(short, bl);
}
#define MFMA16(a, b, c) __builtin_amdgcn_mfma_f32_16x16x32_bf16(a, b, c, 0, 0, 0)

// ---------------- prep: Q, WmsgT (for pass3) + MFMA weight fragment packs.
// Pack layout per GEMM: idx = ((nt*KF + kf)*64 + lane)*8 + j
//   holds W[k][n] with k = kf*32 + 8*(lane>>4) + j, n = nt*16 + (lane&15).
// A and B use the SAME k bijection -> result invariant to the HW's actual k map.
__global__ void prep_kernel(const float* __restrict__ W_msg, const float* __restrict__ W_val,
                            const float* __restrict__ W_out, const float* __restrict__ W_rbf,
                            const float* __restrict__ W_gate,
                            float* __restrict__ Q, float* __restrict__ WmsgT,
                            short* __restrict__ Wp1h, short* __restrict__ Wp1l,
                            short* __restrict__ Wp2h, short* __restrict__ Wp2l,
                            short* __restrict__ Wp3h, short* __restrict__ Wp3l) {
  int i = blockIdx.x * blockDim.x + threadIdx.x;  // grid = 128*256 = 32768
  if (i < 1024) {
    int c = i >> 3, h = i & 7;
    float s = 0.0f;
#pragma unroll
    for (int dv = 0; dv < 16; ++dv)
      s += W_val[c * 128 + h * 16 + dv] * W_out[h * 16 + dv];
    Q[c * 8 + h] = s;
  }
  if (i < 16384) {
    int c = i >> 7, k = i & 127;
    WmsgT[c * 128 + k] = W_msg[k * 128 + c];
  }
  const float* W; short* ph; short* pl; int KF, Nw, local;
  if (i < 8192)       { W = W_rbf;  ph = Wp1h; pl = Wp1l; KF = 4; Nw = 64;  local = i; }
  else if (i < 16384) { W = W_gate; ph = Wp2h; pl = Wp2l; KF = 2; Nw = 128; local = i - 8192; }
  else                { W = W_msg;  ph = Wp3h; pl = Wp3l; KF = 4; Nw = 128; local = i - 16384; }
  int tile = local >> 9;           // nt*KF + kf
  int ln = (local >> 3) & 63;
  int j = local & 7;
  int nt = tile / KF, kf = tile % KF;
  int k = kf * 32 + 8 * (ln >> 4) + j;
  int n = nt * 16 + (ln & 15);
  float w = W[k * Nw + n];
  short h, lo;
  f32_hilo(w, h, lo);
  ph[local] = h;
  pl[local] = lo;
}

// ---------------- pass1 (MFMA): gate (bf16 ws), logits, segment-max
// 4 waves/block, 16 edges/wave. A-frag: edge on lane&15, k on (lane>>4, reg).
// D-frag (m89): col = lane&15 (n), row = 4*(lane>>4)+reg (edge).
__global__ __launch_bounds__(256) void pass1_kernel(
    const float* __restrict__ nb, const int* __restrict__ zn,
    const float* __restrict__ dist, const int* __restrict__ ei,
    const float* __restrict__ wig, const float* __restrict__ aemb,
    const float* __restrict__ alpha,
    const short* __restrict__ Wp1h, const short* __restrict__ Wp1l,
    const short* __restrict__ Wp2h, const short* __restrict__ Wp2l,
    const short* __restrict__ Wp3h, const short* __restrict__ Wp3l,
    float* __restrict__ logits, unsigned int* __restrict__ m_enc,
    __hip_bfloat16* __restrict__ gate_ws) {
  // per-wave LDS tiles; row strides 68/132 floats keep rows 16B-aligned and
  // bank-balanced for the b128 A-frag reads.
  __shared__ __attribute__((aligned(16))) float es_s[4][16][68];
  __shared__ __attribute__((aligned(16))) float xc_s[4][16][132];
  const int tid = threadIdx.x;
  const int lane = tid & 63;
  const int wid = tid >> 6;
  const int g = lane >> 4;
  const int col = lane & 15;
  const int e0 = (blockIdx.x * 4 + wid) * 16;

  // ---- gather x_s0/x_t0 into xc_s (issued first: latency overlaps GEMM1/2) ----
#pragma unroll 4
  for (int e = 0; e < 16; ++e) {
    int eu = e0 + e; if (eu >= NE) eu = NE - 1;
    int se = __builtin_amdgcn_readfirstlane(ei[eu]);
    int de = __builtin_amdgcn_readfirstlane(ei[NE + eu]);
    const float* __restrict__ pw = wig + (size_t)eu * 81;
    const float* __restrict__ ps = nb + (size_t)se * 576 + lane;
    const float* __restrict__ pt = nb + (size_t)de * 576 + lane;
    float xs = 0.0f, xt = 0.0f;
#pragma unroll
    for (int j = 0; j < 9; ++j) {
      float wj = pw[j];
      xs += wj * ps[j * 64];
      xt += wj * pt[j * 64];
    }
    xc_s[wid][e][lane] = xs;
    xc_s[wid][e][64 + lane] = xt;
  }

  // ---- rbf A-frags (computed directly in fragment layout) ----
  int ecol = e0 + col; if (ecol >= NE) ecol = NE - 1;
  const float d = dist[ecol];
  short8v a1h[4], a1l[4];
#pragma unroll
  for (int kf = 0; kf < 4; ++kf) {
#pragma unroll
    for (int j = 0; j < 8; ++j) {
      int k = kf * 32 + 8 * g + j;
      float t = d - (float)k * (1.0f / 127.0f);
      float v = __expf(-8192.0f * t * t);  // width = 1/128 -> 1/(2w^2) = 8192
      short h, lo; f32_hilo(v, h, lo);
      a1h[kf][j] = h; a1l[kf][j] = lo;
    }
  }

  const float4v z4 = {0.0f, 0.0f, 0.0f, 0.0f};

  // ---- GEMM1: es_raw(16x64) = rbf(16x128) @ W_rbf ----
  float4v acc1[4];
#pragma unroll
  for (int nt = 0; nt < 4; ++nt) {
    float4v a = z4;
#pragma unroll
    for (int kf = 0; kf < 4; ++kf) {
      short8v bh = *(const short8v*)(Wp1h + ((nt * 4 + kf) * 64 + lane) * 8);
      short8v bl = *(const short8v*)(Wp1l + ((nt * 4 + kf) * 64 + lane) * 8);
      a = MFMA16(a1h[kf], bh, a);
      a = MFMA16(a1h[kf], bl, a);
      a = MFMA16(a1l[kf], bh, a);
    }
    acc1[nt] = a;
  }

  // ---- bias (atom embeddings) + silu -> es_s ----
  int dn_r[4];
#pragma unroll
  for (int r = 0; r < 4; ++r) {
    int er = e0 + 4 * g + r;
    int erc = er < NE ? er : NE - 1;
    int sn = ei[erc];
    dn_r[r] = ei[NE + erc];
    int zs = zn[sn], zd = zn[dn_r[r]];
#pragma unroll
    for (int nt = 0; nt < 4; ++nt) {
      float b = aemb[zs * 64 + nt * 16 + col] + aemb[zd * 64 + nt * 16 + col];
      es_s[wid][4 * g + r][nt * 16 + col] = silu_f(acc1[nt][r] + b);
    }
  }
  __syncthreads();  // covers es_s and xc_s write->read (cross-lane, same wave)

  // ---- GEMM2 A-frags from es_s ----
  short8v a2h[2], a2l[2];
#pragma unroll
  for (int kf = 0; kf < 2; ++kf) {
    const float* p = &es_s[wid][col][kf * 32 + 8 * g];
    float4v v0 = *(const float4v*)p;
    float4v v1 = *(const float4v*)(p + 4);
#pragma unroll
    for (int j = 0; j < 4; ++j) {
      short h, lo;
      f32_hilo(v0[j], h, lo); a2h[kf][j] = h;     a2l[kf][j] = lo;
      f32_hilo(v1[j], h, lo); a2h[kf][4 + j] = h; a2l[kf][4 + j] = lo;
    }
  }

  // ---- GEMM2: gate(16x128) = es(16x64) @ W_gate, silu, store bf16 ----
  float gate_r[8][4];
#pragma unroll
  for (int nt = 0; nt < 8; ++nt) {
    float4v a = z4;
#pragma unroll
    for (int kf = 0; kf < 2; ++kf) {
      short8v bh = *(const short8v*)(Wp2h + ((nt * 2 + kf) * 64 + lane) * 8);
      short8v bl = *(const short8v*)(Wp2l + ((nt * 2 + kf) * 64 + lane) * 8);
      a = MFMA16(a2h[kf], bh, a);
      a = MFMA16(a2h[kf], bl, a);
      a = MFMA16(a2l[kf], bh, a);
    }
#pragma unroll
    for (int r = 0; r < 4; ++r) {
      float gv = silu_f(a[r]);
      gate_r[nt][r] = gv;
      int er = e0 + 4 * g + r;
      if (er < NE)
        gate_ws[(size_t)er * 128 + nt * 16 + col] = __float2bfloat16(gv);
    }
  }

  // ---- GEMM3 A-frags from xc_s ----
  short8v a3h[4], a3l[4];
#pragma unroll
  for (int kf = 0; kf < 4; ++kf) {
    const float* p = &xc_s[wid][col][kf * 32 + 8 * g];
    float4v v0 = *(const float4v*)p;
    float4v v1 = *(const float4v*)(p + 4);
#pragma unroll
    for (int j = 0; j < 4; ++j) {
      short h, lo;
      f32_hilo(v0[j], h, lo); a3h[kf][j] = h;     a3l[kf][j] = lo;
      f32_hilo(v1[j], h, lo); a3h[kf][4 + j] = h; a3l[kf][4 + j] = lo;
    }
  }

  // ---- GEMM3: msg0(16x128) = xcat(16x128) @ W_msg ; epilogue: logits ----
#pragma unroll
  for (int nt = 0; nt < 8; ++nt) {
    float4v a = z4;
#pragma unroll
    for (int kf = 0; kf < 4; ++kf) {
      short8v bh = *(const short8v*)(Wp3h + ((nt * 4 + kf) * 64 + lane) * 8);
      short8v bl = *(const short8v*)(Wp3l + ((nt * 4 + kf) * 64 + lane) * 8);
      a = MFMA16(a3h[kf], bh, a);
      a = MFMA16(a3h[kf], bl, a);
      a = MFMA16(a3l[kf], bh, a);
    }
    // head h == nt (16 channels per head == one 16-col MFMA tile)
    float al = alpha[nt * 16 + col];
#pragma unroll
    for (int r = 0; r < 4; ++r) {
      float v = a[r] * gate_r[nt][r];
      v = v > 0.0f ? v : 0.2f * v;  // leaky_relu(0.2)
      v *= al;
#pragma unroll
      for (int off = 1; off < 16; off <<= 1) v += __shfl_xor(v, off);
      int er = e0 + 4 * g + r;
      if (col == 0 && er < NE) {
        logits[(size_t)er * 8 + nt] = v;
        atomicMax(&m_enc[dn_r[r] * 8 + nt], enc_f(v));
      }
    }
  }
}

// ---------------- pass2: den[n,h] += exp(logit - m[n,h])
__global__ void pass2_kernel(const float* __restrict__ logits,
                             const int* __restrict__ ei,
                             const unsigned int* __restrict__ m_enc,
                             float* __restrict__ den) {
  int i = blockIdx.x * blockDim.x + threadIdx.x;
  if (i >= NE * 8) return;
  int e = i >> 3, h = i & 7;
  int dn = ei[NE + e];
  float mm = dec_f(m_enc[dn * 8 + h]);
  atomicAdd(&den[dn * 8 + h], __expf(logits[i] - mm));
}

// ---------------- pass3: folded message/value/force computation (unchanged)
__global__ __launch_bounds__(256) void pass3_kernel(
    const float* __restrict__ nb, const int* __restrict__ ei,
    const float* __restrict__ wig, const float* __restrict__ logits,
    const unsigned int* __restrict__ m_enc, const float* __restrict__ den,
    const __hip_bfloat16* __restrict__ gate_ws, const float* __restrict__ Q,
    const float* __restrict__ WmsgT, float* __restrict__ out) {
  const int lane = threadIdx.x & 63;
  const int wid = threadIdx.x >> 6;
  const int e0 = (blockIdx.x * 4 + wid) * 4;

  int src[4], dst[4];
#pragma unroll
  for (int e = 0; e < 4; ++e) {
    src[e] = ei[e0 + e];
    dst[e] = ei[NE + e0 + e];
  }

  float attn_v = 0.0f;
  if (lane < 32) {
    int e = lane >> 3, h = lane & 7;
    int dn = ei[NE + e0 + e];
    float l = logits[(size_t)(e0 + e) * 8 + h];
    float mm = dec_f(m_enc[dn * 8 + h]);
    float dv = den[dn * 8 + h];
    attn_v = __expf(l - mm) / (dv + 1e-9f);
  }

  float g0[4], g1[4];
#pragma unroll
  for (int e = 0; e < 4; ++e) {
    g0[e] = __bfloat162float(gate_ws[(size_t)(e0 + e) * 128 + lane]);
    g1[e] = __bfloat162float(gate_ws[(size_t)(e0 + e) * 128 + 64 + lane]);
  }

  float wv0[4] = {0, 0, 0, 0}, wv1[4] = {0, 0, 0, 0};
#pragma unroll
  for (int h = 0; h < 8; ++h) {
    float q0 = Q[lane * 8 + h];
    float q1 = Q[(lane + 64) * 8 + h];
#pragma unroll
    for (int e = 0; e < 4; ++e) {
      float a = bcast(attn_v, e * 8 + h);
      wv0[e] += q0 * a;
      wv1[e] += q1 * a;
    }
  }
  float u0[4], u1[4];
#pragma unroll
  for (int e = 0; e < 4; ++e) {
    u0[e] = g0[e] * wv0[e];
    u1[e] = g1[e] * wv1[e];
  }

  float t0[4] = {0, 0, 0, 0}, t1[4] = {0, 0, 0, 0};
#pragma unroll 8
  for (int c = 0; c < 64; ++c) {
    float w00 = WmsgT[c * 128 + lane];
    float w01 = WmsgT[c * 128 + 64 + lane];
    float w10 = WmsgT[(c + 64) * 128 + lane];
    float w11 = WmsgT[(c + 64) * 128 + 64 + lane];
#pragma unroll
    for (int e = 0; e < 4; ++e) {
      float a0 = bcast(u0[e], c);
      float a1 = bcast(u1[e], c);
      t0[e] += a0 * w00 + a1 * w10;
      t1[e] += a0 * w01 + a1 * w11;
    }
  }

#pragma unroll
  for (int e = 0; e < 4; ++e) {
    const float* ps = nb + (size_t)src[e] * 576 + lane;
    const float* pt = nb + (size_t)dst[e] * 576 + lane;
    float dj[9];
#pragma unroll
    for (int j = 0; j < 9; ++j) {
      float p = ps[j * 64] * t0[e] + pt[j * 64] * t1[e];
#pragma unroll
      for (int off = 32; off >= 1; off >>= 1) p += __shfl_xor(p, off);
      dj[j] = p;
    }
    const float* we = wig + (size_t)(e0 + e) * 81;
    float s_j = 0.0f;
    if (lane < 9) {
#pragma unroll
      for (int jp = 0; jp < 9; ++jp) s_j += we[lane * 9 + jp] * dj[jp];
    }
    if (lane >= 1 && lane <= 3) {
      float f = 0.0f;
#pragma unroll
      for (int j = 0; j < 9; ++j) f += bcast(s_j, j) * we[j * 9 + lane];
      atomicAdd(&out[dst[e] * 3 + (lane - 1)], f);
    }
  }
}

extern "C" void kernel_launch(void* const* d_in, const int* in_sizes, int n_in,
                              void* d_out, int out_size, void* d_ws, size_t ws_size,
                              hipStream_t stream) {
  const float* nb = (const float*)d_in[0];
  const int* zn = (const int*)d_in[1];
  const float* dist = (const float*)d_in[2];
  const int* ei = (const int*)d_in[3];
  const float* wig = (const float*)d_in[4];
  const float* aemb = (const float*)d_in[5];
  const float* W_rbf = (const float*)d_in[6];
  const float* W_gate = (const float*)d_in[7];
  const float* W_msg = (const float*)d_in[8];
  const float* alpha = (const float*)d_in[9];
  const float* W_val = (const float*)d_in[10];
  const float* W_out = (const float*)d_in[11];
  float* out = (float*)d_out;

  // workspace layout (~29.7 MB)
  char* p = (char*)d_ws;
  float* Q = (float*)p;                   p += 1024 * 4;
  float* WmsgT = (float*)p;               p += 16384 * 4;
  unsigned int* m_enc = (unsigned int*)p; p += (size_t)NN * 8 * 4;
  float* den = (float*)p;                 p += (size_t)NN * 8 * 4;
  float* logits = (float*)p;              p += (size_t)NE * 8 * 4;
  __hip_bfloat16* gate_ws = (__hip_bfloat16*)p; p += (size_t)NE * 128 * 2;
  short* Wp1h = (short*)p; p += 8192 * 2;
  short* Wp1l = (short*)p; p += 8192 * 2;
  short* Wp2h = (short*)p; p += 8192 * 2;
  short* Wp2l = (short*)p; p += 8192 * 2;
  short* Wp3h = (short*)p; p += 16384 * 2;
  short* Wp3l = (short*)p; p += 16384 * 2;

  hipMemsetAsync(d_out, 0, (size_t)NN * 3 * 4, stream);
  hipMemsetAsync(m_enc, 0, (size_t)NN * 8 * 4, stream);
  hipMemsetAsync(den, 0, (size_t)NN * 8 * 4, stream);

  prep_kernel<<<128, 256, 0, stream>>>(W_msg, W_val, W_out, W_rbf, W_gate, Q, WmsgT,
                                       Wp1h, Wp1l, Wp2h, Wp2l, Wp3h, Wp3l);
  pass1_kernel<<<(NE + 63) / 64, 256, 0, stream>>>(nb, zn, dist, ei, wig, aemb, alpha,
                                                   Wp1h, Wp1l, Wp2h, Wp2l, Wp3h, Wp3l,
                                                   logits, m_enc, gate_ws);
  pass2_kernel<<<(NE * 8) / 256, 256, 0, stream>>>(logits, ei, m_enc, den);
  pass3_kernel<<<NE / 16, 256, 0, stream>>>(nb, ei, wig, logits, m_enc, den,
                                            gate_ws, Q, WmsgT, out);
}

// Round 3
// 325.206 us; speedup vs baseline: 1.4221x; 1.0953x over previous
//
#include <hip/hip_runtime.h>
#include <hip/hip_bf16.h>

#define NN 10000
#define NE 100000

typedef __attribute__((ext_vector_type(8))) short short8v;
typedef __attribute__((ext_vector_type(4))) float float4v;

__device__ __forceinline__ float bcast(float v, int k) {
  return __int_as_float(__builtin_amdgcn_readlane(__float_as_int(v), k));
}
__device__ __forceinline__ unsigned int enc_f(float f) {
  unsigned int u = __float_as_uint(f);
  return (u & 0x80000000u) ? ~u : (u | 0x80000000u);
}
__device__ __forceinline__ float dec_f(unsigned int u) {
  return __uint_as_float((u & 0x80000000u) ? (u & 0x7fffffffu) : ~u);
}
__device__ __forceinline__ float silu_f(float x) {
  return x / (1.0f + __expf(-x));
}
// fp32 -> bf16 hi/lo split: x ~= hi + lo with ~2^-16 relative error.
__device__ __forceinline__ void f32_hilo(float x, short& h, short& l) {
  __hip_bfloat16 bh = __float2bfloat16(x);
  float r = x - __bfloat162float(bh);
  __hip_bfloat16 bl = __float2bfloat16(r);
  h = __builtin_bit_cast(short, bh);
  l = __builtin_bit_cast(short, bl);
}
#define MFMA16(a, b, c) __builtin_amdgcn_mfma_f32_16x16x32_bf16(a, b, c, 0, 0, 0)

// ---------------- prep: Q + MFMA weight fragment packs.
// Pack layout per GEMM: idx = ((nt*KF + kf)*64 + lane)*8 + j
//   holds W[k][n] with k = kf*32 + 8*(lane>>4) + j, n = nt*16 + (lane&15).
// A and B use the SAME k bijection -> result invariant to the HW's actual k map.
// Wp4 packs W_msg TRANSPOSED: B[k=m][n=c2] = W_msg[c2*128 + m]  (t = u @ W_msg^T).
__global__ void prep_kernel(const float* __restrict__ W_msg, const float* __restrict__ W_val,
                            const float* __restrict__ W_out, const float* __restrict__ W_rbf,
                            const float* __restrict__ W_gate,
                            float* __restrict__ Q,
                            short* __restrict__ Wp1h, short* __restrict__ Wp1l,
                            short* __restrict__ Wp2h, short* __restrict__ Wp2l,
                            short* __restrict__ Wp3h, short* __restrict__ Wp3l,
                            short* __restrict__ Wp4h, short* __restrict__ Wp4l) {
  int i = blockIdx.x * blockDim.x + threadIdx.x;  // grid = 192*256 = 49152
  if (i < 1024) {
    int c = i >> 3, h = i & 7;
    float s = 0.0f;
#pragma unroll
    for (int dv = 0; dv < 16; ++dv)
      s += W_val[c * 128 + h * 16 + dv] * W_out[h * 16 + dv];
    Q[c * 8 + h] = s;
  }
  const float* W; short* ph; short* pl; int KF, Nw, local; bool tr = false;
  if (i < 8192)       { W = W_rbf;  ph = Wp1h; pl = Wp1l; KF = 4; Nw = 64;  local = i; }
  else if (i < 16384) { W = W_gate; ph = Wp2h; pl = Wp2l; KF = 2; Nw = 128; local = i - 8192; }
  else if (i < 32768) { W = W_msg;  ph = Wp3h; pl = Wp3l; KF = 4; Nw = 128; local = i - 16384; }
  else                { W = W_msg;  ph = Wp4h; pl = Wp4l; KF = 4; Nw = 128; local = i - 32768; tr = true; }
  int tile = local >> 9;           // nt*KF + kf
  int ln = (local >> 3) & 63;
  int j = local & 7;
  int nt = tile / KF, kf = tile % KF;
  int k = kf * 32 + 8 * (ln >> 4) + j;
  int n = nt * 16 + (ln & 15);
  float w = tr ? W[n * 128 + k] : W[k * Nw + n];
  short h, lo;
  f32_hilo(w, h, lo);
  ph[local] = h;
  pl[local] = lo;
}

// ---------------- pass1 (MFMA): gate (bf16 ws), logits, segment-max  [unchanged]
__global__ __launch_bounds__(256) void pass1_kernel(
    const float* __restrict__ nb, const int* __restrict__ zn,
    const float* __restrict__ dist, const int* __restrict__ ei,
    const float* __restrict__ wig, const float* __restrict__ aemb,
    const float* __restrict__ alpha,
    const short* __restrict__ Wp1h, const short* __restrict__ Wp1l,
    const short* __restrict__ Wp2h, const short* __restrict__ Wp2l,
    const short* __restrict__ Wp3h, const short* __restrict__ Wp3l,
    float* __restrict__ logits, unsigned int* __restrict__ m_enc,
    __hip_bfloat16* __restrict__ gate_ws) {
  __shared__ __attribute__((aligned(16))) float es_s[4][16][68];
  __shared__ __attribute__((aligned(16))) float xc_s[4][16][132];
  const int tid = threadIdx.x;
  const int lane = tid & 63;
  const int wid = tid >> 6;
  const int g = lane >> 4;
  const int col = lane & 15;
  const int e0 = (blockIdx.x * 4 + wid) * 16;

#pragma unroll 4
  for (int e = 0; e < 16; ++e) {
    int eu = e0 + e; if (eu >= NE) eu = NE - 1;
    int se = __builtin_amdgcn_readfirstlane(ei[eu]);
    int de = __builtin_amdgcn_readfirstlane(ei[NE + eu]);
    const float* __restrict__ pw = wig + (size_t)eu * 81;
    const float* __restrict__ ps = nb + (size_t)se * 576 + lane;
    const float* __restrict__ pt = nb + (size_t)de * 576 + lane;
    float xs = 0.0f, xt = 0.0f;
#pragma unroll
    for (int j = 0; j < 9; ++j) {
      float wj = pw[j];
      xs += wj * ps[j * 64];
      xt += wj * pt[j * 64];
    }
    xc_s[wid][e][lane] = xs;
    xc_s[wid][e][64 + lane] = xt;
  }

  int ecol = e0 + col; if (ecol >= NE) ecol = NE - 1;
  const float d = dist[ecol];
  short8v a1h[4], a1l[4];
#pragma unroll
  for (int kf = 0; kf < 4; ++kf) {
#pragma unroll
    for (int j = 0; j < 8; ++j) {
      int k = kf * 32 + 8 * g + j;
      float t = d - (float)k * (1.0f / 127.0f);
      float v = __expf(-8192.0f * t * t);
      short h, lo; f32_hilo(v, h, lo);
      a1h[kf][j] = h; a1l[kf][j] = lo;
    }
  }

  const float4v z4 = {0.0f, 0.0f, 0.0f, 0.0f};

  float4v acc1[4];
#pragma unroll
  for (int nt = 0; nt < 4; ++nt) {
    float4v a = z4;
#pragma unroll
    for (int kf = 0; kf < 4; ++kf) {
      short8v bh = *(const short8v*)(Wp1h + ((nt * 4 + kf) * 64 + lane) * 8);
      short8v bl = *(const short8v*)(Wp1l + ((nt * 4 + kf) * 64 + lane) * 8);
      a = MFMA16(a1h[kf], bh, a);
      a = MFMA16(a1h[kf], bl, a);
      a = MFMA16(a1l[kf], bh, a);
    }
    acc1[nt] = a;
  }

  int dn_r[4];
#pragma unroll
  for (int r = 0; r < 4; ++r) {
    int er = e0 + 4 * g + r;
    int erc = er < NE ? er : NE - 1;
    int sn = ei[erc];
    dn_r[r] = ei[NE + erc];
    int zs = zn[sn], zd = zn[dn_r[r]];
#pragma unroll
    for (int nt = 0; nt < 4; ++nt) {
      float b = aemb[zs * 64 + nt * 16 + col] + aemb[zd * 64 + nt * 16 + col];
      es_s[wid][4 * g + r][nt * 16 + col] = silu_f(acc1[nt][r] + b);
    }
  }
  __syncthreads();

  short8v a2h[2], a2l[2];
#pragma unroll
  for (int kf = 0; kf < 2; ++kf) {
    const float* p = &es_s[wid][col][kf * 32 + 8 * g];
    float4v v0 = *(const float4v*)p;
    float4v v1 = *(const float4v*)(p + 4);
#pragma unroll
    for (int j = 0; j < 4; ++j) {
      short h, lo;
      f32_hilo(v0[j], h, lo); a2h[kf][j] = h;     a2l[kf][j] = lo;
      f32_hilo(v1[j], h, lo); a2h[kf][4 + j] = h; a2l[kf][4 + j] = lo;
    }
  }

  float gate_r[8][4];
#pragma unroll
  for (int nt = 0; nt < 8; ++nt) {
    float4v a = z4;
#pragma unroll
    for (int kf = 0; kf < 2; ++kf) {
      short8v bh = *(const short8v*)(Wp2h + ((nt * 2 + kf) * 64 + lane) * 8);
      short8v bl = *(const short8v*)(Wp2l + ((nt * 2 + kf) * 64 + lane) * 8);
      a = MFMA16(a2h[kf], bh, a);
      a = MFMA16(a2h[kf], bl, a);
      a = MFMA16(a2l[kf], bh, a);
    }
#pragma unroll
    for (int r = 0; r < 4; ++r) {
      float gv = silu_f(a[r]);
      gate_r[nt][r] = gv;
      int er = e0 + 4 * g + r;
      if (er < NE)
        gate_ws[(size_t)er * 128 + nt * 16 + col] = __float2bfloat16(gv);
    }
  }

  short8v a3h[4], a3l[4];
#pragma unroll
  for (int kf = 0; kf < 4; ++kf) {
    const float* p = &xc_s[wid][col][kf * 32 + 8 * g];
    float4v v0 = *(const float4v*)p;
    float4v v1 = *(const float4v*)(p + 4);
#pragma unroll
    for (int j = 0; j < 4; ++j) {
      short h, lo;
      f32_hilo(v0[j], h, lo); a3h[kf][j] = h;     a3l[kf][j] = lo;
      f32_hilo(v1[j], h, lo); a3h[kf][4 + j] = h; a3l[kf][4 + j] = lo;
    }
  }

#pragma unroll
  for (int nt = 0; nt < 8; ++nt) {
    float4v a = z4;
#pragma unroll
    for (int kf = 0; kf < 4; ++kf) {
      short8v bh = *(const short8v*)(Wp3h + ((nt * 4 + kf) * 64 + lane) * 8);
      short8v bl = *(const short8v*)(Wp3l + ((nt * 4 + kf) * 64 + lane) * 8);
      a = MFMA16(a3h[kf], bh, a);
      a = MFMA16(a3h[kf], bl, a);
      a = MFMA16(a3l[kf], bh, a);
    }
    float al = alpha[nt * 16 + col];
#pragma unroll
    for (int r = 0; r < 4; ++r) {
      float v = a[r] * gate_r[nt][r];
      v = v > 0.0f ? v : 0.2f * v;
      v *= al;
#pragma unroll
      for (int off = 1; off < 16; off <<= 1) v += __shfl_xor(v, off);
      int er = e0 + 4 * g + r;
      if (col == 0 && er < NE) {
        logits[(size_t)er * 8 + nt] = v;
        atomicMax(&m_enc[dn_r[r] * 8 + nt], enc_f(v));
      }
    }
  }
}

// ---------------- pass2: den[n,h] += exp(logit - m[n,h])  [unchanged]
__global__ void pass2_kernel(const float* __restrict__ logits,
                             const int* __restrict__ ei,
                             const unsigned int* __restrict__ m_enc,
                             float* __restrict__ den) {
  int i = blockIdx.x * blockDim.x + threadIdx.x;
  if (i >= NE * 8) return;
  int e = i >> 3, h = i & 7;
  int dn = ei[NE + e];
  float mm = dec_f(m_enc[dn * 8 + h]);
  atomicAdd(&den[dn * 8 + h], __expf(logits[i] - mm));
}

// ---------------- pass3 (MFMA): folded message/value/force
// 16 edges/wave. t(16x128) = u(16x128) @ W_msg^T via MFMA (Wp4).
// All LDS tiles are per-wave ([wid]) -> within-wave ordering only, no barriers.
__global__ __launch_bounds__(256) void pass3_kernel(
    const float* __restrict__ nb, const int* __restrict__ ei,
    const float* __restrict__ wig, const float* __restrict__ logits,
    const unsigned int* __restrict__ m_enc, const float* __restrict__ den,
    const __hip_bfloat16* __restrict__ gate_ws, const float* __restrict__ Q,
    const short* __restrict__ Wp4h, const short* __restrict__ Wp4l,
    float* __restrict__ out) {
  __shared__ __attribute__((aligned(16))) float attn_s[4][16][8];
  __shared__ __attribute__((aligned(16))) float x_s[4][16][132];  // u, then t
  const int tid = threadIdx.x;
  const int lane = tid & 63;
  const int wid = tid >> 6;
  const int g = lane >> 4;
  const int col = lane & 15;
  const int e0 = (blockIdx.x * 4 + wid) * 16;

  // ---- phase A: attn for 16 edges x 8 heads (2 (e,h) pairs per lane) ----
#pragma unroll
  for (int half = 0; half < 2; ++half) {
    int i = half * 64 + lane;
    int e = i >> 3, h = i & 7;
    int ec = e0 + e; if (ec >= NE) ec = NE - 1;
    int dn = ei[NE + ec];
    float l = logits[(size_t)ec * 8 + h];
    float mm = dec_f(m_enc[dn * 8 + h]);
    float dv = den[dn * 8 + h];
    attn_s[wid][e][h] = __expf(l - mm) / (dv + 1e-9f);
  }

  // ---- phase B: u[e, m] = gate[e,m] * sum_h Q[m,h] attn[e,h] ; m = lane, lane+64 ----
  float q0[8], q1[8];
#pragma unroll
  for (int h = 0; h < 8; ++h) {
    q0[h] = Q[lane * 8 + h];
    q1[h] = Q[(lane + 64) * 8 + h];
  }
#pragma unroll 4
  for (int e = 0; e < 16; ++e) {
    int ec = e0 + e; if (ec >= NE) ec = NE - 1;
    float4v a0 = *(const float4v*)&attn_s[wid][e][0];
    float4v a1 = *(const float4v*)&attn_s[wid][e][4];
    float wv0 = 0.0f, wv1 = 0.0f;
#pragma unroll
    for (int h = 0; h < 4; ++h) {
      wv0 += q0[h] * a0[h] + q0[4 + h] * a1[h];
      wv1 += q1[h] * a0[h] + q1[4 + h] * a1[h];
    }
    float gg0 = __bfloat162float(gate_ws[(size_t)ec * 128 + lane]);
    float gg1 = __bfloat162float(gate_ws[(size_t)ec * 128 + 64 + lane]);
    x_s[wid][e][lane] = gg0 * wv0;
    x_s[wid][e][64 + lane] = gg1 * wv1;
  }

  // ---- phase C: A-frags from u, then T = U @ Wp4 (96 MFMA), t -> x_s ----
  short8v ah[4], al[4];
#pragma unroll
  for (int kf = 0; kf < 4; ++kf) {
    const float* p = &x_s[wid][col][kf * 32 + 8 * g];
    float4v v0 = *(const float4v*)p;
    float4v v1 = *(const float4v*)(p + 4);
#pragma unroll
    for (int j = 0; j < 4; ++j) {
      short h, lo;
      f32_hilo(v0[j], h, lo); ah[kf][j] = h;     al[kf][j] = lo;
      f32_hilo(v1[j], h, lo); ah[kf][4 + j] = h; al[kf][4 + j] = lo;
    }
  }
  const float4v z4 = {0.0f, 0.0f, 0.0f, 0.0f};
  float4v acc[8];
#pragma unroll
  for (int nt = 0; nt < 8; ++nt) {
    float4v a = z4;
#pragma unroll
    for (int kf = 0; kf < 4; ++kf) {
      short8v bh = *(const short8v*)(Wp4h + ((nt * 4 + kf) * 64 + lane) * 8);
      short8v bl = *(const short8v*)(Wp4l + ((nt * 4 + kf) * 64 + lane) * 8);
      a = MFMA16(ah[kf], bh, a);
      a = MFMA16(ah[kf], bl, a);
      a = MFMA16(al[kf], bh, a);
    }
    acc[nt] = a;
  }
  // D-frag: row(edge) = 4g+r, col(n) = nt*16+col
#pragma unroll
  for (int nt = 0; nt < 8; ++nt)
#pragma unroll
    for (int r = 0; r < 4; ++r)
      x_s[wid][4 * g + r][nt * 16 + col] = acc[nt][r];

  // ---- phase D: d[j'] dots + wigner epilogue; 4 edges in parallel (16 lanes each) ----
  const int cg = col * 4;  // 4 channels per lane
#pragma unroll
  for (int it = 0; it < 4; ++it) {
    int e = it * 4 + g;
    int eu = e0 + e;
    bool valid = eu < NE;
    int ec = valid ? eu : NE - 1;
    int se = ei[ec], de = ei[NE + ec];
    float4v t0 = *(const float4v*)&x_s[wid][e][cg];
    float4v t1 = *(const float4v*)&x_s[wid][e][64 + cg];
    const float* ps = nb + (size_t)se * 576 + cg;
    const float* pt = nb + (size_t)de * 576 + cg;
    float dj[9];
#pragma unroll
    for (int j = 0; j < 9; ++j) {
      float4v a = *(const float4v*)(ps + j * 64);
      float4v b = *(const float4v*)(pt + j * 64);
      dj[j] = a[0] * t0[0] + a[1] * t0[1] + a[2] * t0[2] + a[3] * t0[3] +
              b[0] * t1[0] + b[1] * t1[1] + b[2] * t1[2] + b[3] * t1[3];
    }
#pragma unroll
    for (int j = 0; j < 9; ++j)
#pragma unroll
      for (int off = 1; off < 16; off <<= 1) dj[j] += __shfl_xor(dj[j], off);

    // s[l] = sum_j' wig[l, j'] d[j']  (lanes l<9 of each group; clamped loads)
    const float* we = wig + (size_t)ec * 81;
    int ls = col < 9 ? col : 8;
    float s_l = 0.0f;
#pragma unroll
    for (int jp = 0; jp < 9; ++jp) s_l += we[ls * 9 + jp] * dj[jp];
    // f_i = sum_j wig[j, i] s[j], i = col in 1..3 (all lanes run the shfl)
    int lc = (col >= 1 && col <= 3) ? col : 1;
    float f = 0.0f;
#pragma unroll
    for (int j = 0; j < 9; ++j)
      f += __shfl(s_l, (lane & 48) + j) * we[j * 9 + lc];
    if (col >= 1 && col <= 3 && valid)
      atomicAdd(&out[de * 3 + (col - 1)], f);
  }
}

extern "C" void kernel_launch(void* const* d_in, const int* in_sizes, int n_in,
                              void* d_out, int out_size, void* d_ws, size_t ws_size,
                              hipStream_t stream) {
  const float* nb = (const float*)d_in[0];
  const int* zn = (const int*)d_in[1];
  const float* dist = (const float*)d_in[2];
  const int* ei = (const int*)d_in[3];
  const float* wig = (const float*)d_in[4];
  const float* aemb = (const float*)d_in[5];
  const float* W_rbf = (const float*)d_in[6];
  const float* W_gate = (const float*)d_in[7];
  const float* W_msg = (const float*)d_in[8];
  const float* alpha = (const float*)d_in[9];
  const float* W_val = (const float*)d_in[10];
  const float* W_out = (const float*)d_in[11];
  float* out = (float*)d_out;

  // workspace layout (~29.8 MB)
  char* p = (char*)d_ws;
  float* Q = (float*)p;                   p += 1024 * 4;
  unsigned int* m_enc = (unsigned int*)p; p += (size_t)NN * 8 * 4;
  float* den = (float*)p;                 p += (size_t)NN * 8 * 4;
  float* logits = (float*)p;              p += (size_t)NE * 8 * 4;
  __hip_bfloat16* gate_ws = (__hip_bfloat16*)p; p += (size_t)NE * 128 * 2;
  short* Wp1h = (short*)p; p += 8192 * 2;
  short* Wp1l = (short*)p; p += 8192 * 2;
  short* Wp2h = (short*)p; p += 8192 * 2;
  short* Wp2l = (short*)p; p += 8192 * 2;
  short* Wp3h = (short*)p; p += 16384 * 2;
  short* Wp3l = (short*)p; p += 16384 * 2;
  short* Wp4h = (short*)p; p += 16384 * 2;
  short* Wp4l = (short*)p; p += 16384 * 2;

  hipMemsetAsync(d_out, 0, (size_t)NN * 3 * 4, stream);
  hipMemsetAsync(m_enc, 0, (size_t)NN * 8 * 4, stream);
  hipMemsetAsync(den, 0, (size_t)NN * 8 * 4, stream);

  prep_kernel<<<192, 256, 0, stream>>>(W_msg, W_val, W_out, W_rbf, W_gate, Q,
                                       Wp1h, Wp1l, Wp2h, Wp2l, Wp3h, Wp3l, Wp4h, Wp4l);
  pass1_kernel<<<(NE + 63) / 64, 256, 0, stream>>>(nb, zn, dist, ei, wig, aemb, alpha,
                                                   Wp1h, Wp1l, Wp2h, Wp2l, Wp3h, Wp3l,
                                                   logits, m_enc, gate_ws);
  pass2_kernel<<<(NE * 8 + 255) / 256, 256, 0, stream>>>(logits, ei, m_enc, den);
  pass3_kernel<<<(NE + 63) / 64, 256, 0, stream>>>(nb, ei, wig, logits, m_enc, den,
                                                   gate_ws, Q, Wp4h, Wp4l, out);
}

// Round 5
// 306.983 us; speedup vs baseline: 1.5065x; 1.0594x over previous
//
#include <hip/hip_runtime.h>
#include <hip/hip_bf16.h>

#define NN 10000
#define NE 100000

typedef __attribute__((ext_vector_type(8))) short short8v;
typedef __attribute__((ext_vector_type(4))) float float4v;

__device__ __forceinline__ float bcast(float v, int k) {
  return __int_as_float(__builtin_amdgcn_readlane(__float_as_int(v), k));
}
// NOTE: readlane requires a WAVE-UNIFORM lane index (compile-time/SGPR).
// Only use bcast_i with unrolled-loop-constant k. For divergent k use __shfl.
__device__ __forceinline__ int bcast_i(int v, int k) {
  return __builtin_amdgcn_readlane(v, k);
}
__device__ __forceinline__ unsigned int enc_f(float f) {
  unsigned int u = __float_as_uint(f);
  return (u & 0x80000000u) ? ~u : (u | 0x80000000u);
}
__device__ __forceinline__ float dec_f(unsigned int u) {
  return __uint_as_float((u & 0x80000000u) ? (u & 0x7fffffffu) : ~u);
}
__device__ __forceinline__ float silu_f(float x) {
  return x / (1.0f + __expf(-x));
}
// fp32 -> bf16 hi/lo split: x ~= hi + lo with ~2^-16 relative error.
__device__ __forceinline__ void f32_hilo(float x, short& h, short& l) {
  __hip_bfloat16 bh = __float2bfloat16(x);
  float r = x - __bfloat162float(bh);
  __hip_bfloat16 bl = __float2bfloat16(r);
  h = __builtin_bit_cast(short, bh);
  l = __builtin_bit_cast(short, bl);
}
#define MFMA16(a, b, c) __builtin_amdgcn_mfma_f32_16x16x32_bf16(a, b, c, 0, 0, 0)

// issue all 27 loads (src row, dst row, wig row) for one edge into reg arrays
// e is an unrolled-loop constant -> readlane index is uniform (legal).
__device__ __forceinline__ void g_issue(const float* __restrict__ nb,
                                        const float* __restrict__ wig,
                                        int idx_v, int e0, int e, int lane,
                                        float (&VS)[9], float (&VT)[9], float (&WJ)[9]) {
  int se_ = bcast_i(idx_v, e);
  int de_ = bcast_i(idx_v, 16 + e);
  int ec_ = (e0 + e < NE) ? e0 + e : NE - 1;
  const float* __restrict__ ps_ = nb + (size_t)se_ * 576 + lane;
  const float* __restrict__ pt_ = nb + (size_t)de_ * 576 + lane;
  const float* __restrict__ pw_ = wig + (size_t)ec_ * 81;
#pragma unroll
  for (int j = 0; j < 9; ++j) {
    VS[j] = ps_[j * 64];
    VT[j] = pt_[j * 64];
    WJ[j] = pw_[j];
  }
}

// ---------------- prep: Q + MFMA weight fragment packs.
// Pack layout per GEMM: idx = ((nt*KF + kf)*64 + lane)*8 + j
//   holds W[k][n] with k = kf*32 + 8*(lane>>4) + j, n = nt*16 + (lane&15).
// A and B use the SAME k bijection -> result invariant to the HW's actual k map.
// Wp4 packs W_msg TRANSPOSED: B[k=m][n=c2] = W_msg[c2*128 + m]  (t = u @ W_msg^T).
__global__ void prep_kernel(const float* __restrict__ W_msg, const float* __restrict__ W_val,
                            const float* __restrict__ W_out, const float* __restrict__ W_rbf,
                            const float* __restrict__ W_gate,
                            float* __restrict__ Q,
                            short* __restrict__ Wp1h, short* __restrict__ Wp1l,
                            short* __restrict__ Wp2h, short* __restrict__ Wp2l,
                            short* __restrict__ Wp3h, short* __restrict__ Wp3l,
                            short* __restrict__ Wp4h, short* __restrict__ Wp4l) {
  int i = blockIdx.x * blockDim.x + threadIdx.x;  // grid = 192*256 = 49152
  if (i < 1024) {
    int c = i >> 3, h = i & 7;
    float s = 0.0f;
#pragma unroll
    for (int dv = 0; dv < 16; ++dv)
      s += W_val[c * 128 + h * 16 + dv] * W_out[h * 16 + dv];
    Q[c * 8 + h] = s;
  }
  const float* W; short* ph; short* pl; int KF, Nw, local; bool tr = false;
  if (i < 8192)       { W = W_rbf;  ph = Wp1h; pl = Wp1l; KF = 4; Nw = 64;  local = i; }
  else if (i < 16384) { W = W_gate; ph = Wp2h; pl = Wp2l; KF = 2; Nw = 128; local = i - 8192; }
  else if (i < 32768) { W = W_msg;  ph = Wp3h; pl = Wp3l; KF = 4; Nw = 128; local = i - 16384; }
  else                { W = W_msg;  ph = Wp4h; pl = Wp4l; KF = 4; Nw = 128; local = i - 32768; tr = true; }
  int tile = local >> 9;           // nt*KF + kf
  int ln = (local >> 3) & 63;
  int j = local & 7;
  int nt = tile / KF, kf = tile % KF;
  int k = kf * 32 + 8 * (ln >> 4) + j;
  int n = nt * 16 + (ln & 15);
  float w = tr ? W[n * 128 + k] : W[k * Nw + n];
  short h, lo;
  f32_hilo(w, h, lo);
  ph[local] = h;
  pl[local] = lo;
}

// ---------------- pass1 (MFMA): gate (bf16 ws), logits, segment-max
// 4 waves/block, 16 edges/wave. Single per-wave LDS buffer (xc then es),
// barrier-free; 2-deep gather software pipeline.
__global__ __launch_bounds__(256, 3) void pass1_kernel(
    const float* __restrict__ nb, const int* __restrict__ zn,
    const float* __restrict__ dist, const int* __restrict__ ei,
    const float* __restrict__ wig, const float* __restrict__ aemb,
    const float* __restrict__ alpha,
    const short* __restrict__ Wp1h, const short* __restrict__ Wp1l,
    const short* __restrict__ Wp2h, const short* __restrict__ Wp2l,
    const short* __restrict__ Wp3h, const short* __restrict__ Wp3l,
    float* __restrict__ logits, unsigned int* __restrict__ m_enc,
    __hip_bfloat16* __restrict__ gate_ws) {
  __shared__ __attribute__((aligned(16))) float xe_s[4][16][132];
  const int tid = threadIdx.x;
  const int lane = tid & 63;
  const int wid = tid >> 6;
  const int g = lane >> 4;
  const int col = lane & 15;
  const int e0 = (blockIdx.x * 4 + wid) * 16;

  // preload the wave's 32 edge indices: lanes 0..15 = src, 16..31 = dst
  int l16 = lane & 15;
  int ecl16 = (e0 + l16 < NE) ? e0 + l16 : NE - 1;
  int idx_v = 0;
  if (lane < 32) idx_v = ei[(lane < 16 ? 0 : NE) + ecl16];

  int ecol = e0 + col; if (ecol >= NE) ecol = NE - 1;
  const float d = dist[ecol];

  // ---- gather x_s0/x_t0 into xe_s, 2-deep pipelined ----
  float vs0[9], vt0[9], wj0[9], vs1[9], vt1[9], wj1[9];
  g_issue(nb, wig, idx_v, e0, 0, lane, vs0, vt0, wj0);
  g_issue(nb, wig, idx_v, e0, 1, lane, vs1, vt1, wj1);
#pragma unroll
  for (int e = 0; e < 16; e += 2) {
    {
      float xs = 0.0f, xt = 0.0f;
#pragma unroll
      for (int j = 0; j < 9; ++j) { xs += wj0[j] * vs0[j]; xt += wj0[j] * vt0[j]; }
      xe_s[wid][e][lane] = xs;
      xe_s[wid][e][64 + lane] = xt;
    }
    if (e + 2 < 16) g_issue(nb, wig, idx_v, e0, e + 2, lane, vs0, vt0, wj0);
    {
      float xs = 0.0f, xt = 0.0f;
#pragma unroll
      for (int j = 0; j < 9; ++j) { xs += wj1[j] * vs1[j]; xt += wj1[j] * vt1[j]; }
      xe_s[wid][e + 1][lane] = xs;
      xe_s[wid][e + 1][64 + lane] = xt;
    }
    if (e + 3 < 16) g_issue(nb, wig, idx_v, e0, e + 3, lane, vs1, vt1, wj1);
  }

  // ---- rbf A-frags (direct in fragment layout) ----
  short8v a1h[4], a1l[4];
#pragma unroll
  for (int kf = 0; kf < 4; ++kf) {
#pragma unroll
    for (int j = 0; j < 8; ++j) {
      int k = kf * 32 + 8 * g + j;
      float t = d - (float)k * (1.0f / 127.0f);
      float v = __expf(-8192.0f * t * t);
      short h, lo; f32_hilo(v, h, lo);
      a1h[kf][j] = h; a1l[kf][j] = lo;
    }
  }

  // ---- A3 frags from xe_s BEFORE es overwrites the buffer ----
  short8v a3h[4], a3l[4];
#pragma unroll
  for (int kf = 0; kf < 4; ++kf) {
    const float* p = &xe_s[wid][col][kf * 32 + 8 * g];
    float4v v0 = *(const float4v*)p;
    float4v v1 = *(const float4v*)(p + 4);
#pragma unroll
    for (int j = 0; j < 4; ++j) {
      short h, lo;
      f32_hilo(v0[j], h, lo); a3h[kf][j] = h;     a3l[kf][j] = lo;
      f32_hilo(v1[j], h, lo); a3h[kf][4 + j] = h; a3l[kf][4 + j] = lo;
    }
  }

  const float4v z4 = {0.0f, 0.0f, 0.0f, 0.0f};

  // ---- GEMM1: es_raw(16x64) = rbf(16x128) @ W_rbf ----
  float4v acc1[4];
#pragma unroll
  for (int nt = 0; nt < 4; ++nt) {
    float4v a = z4;
#pragma unroll
    for (int kf = 0; kf < 4; ++kf) {
      short8v bh = *(const short8v*)(Wp1h + ((nt * 4 + kf) * 64 + lane) * 8);
      short8v bl = *(const short8v*)(Wp1l + ((nt * 4 + kf) * 64 + lane) * 8);
      a = MFMA16(a1h[kf], bh, a);
      a = MFMA16(a1h[kf], bl, a);
      a = MFMA16(a1l[kf], bh, a);
    }
    acc1[nt] = a;
  }

  // ---- bias + silu -> es rows (reuse xe_s; per-wave in-order LDS) ----
  // __shfl (ds_bpermute) handles the divergent 4*g+r source lane; readlane does NOT.
  int dn_r[4];
#pragma unroll
  for (int r = 0; r < 4; ++r) {
    int sn = __shfl(idx_v, 4 * g + r);
    dn_r[r] = __shfl(idx_v, 16 + 4 * g + r);
    int zs = zn[sn], zd = zn[dn_r[r]];
#pragma unroll
    for (int nt = 0; nt < 4; ++nt) {
      float b = aemb[zs * 64 + nt * 16 + col] + aemb[zd * 64 + nt * 16 + col];
      xe_s[wid][4 * g + r][nt * 16 + col] = silu_f(acc1[nt][r] + b);
    }
  }

  // ---- GEMM2 A-frags from es rows ----
  short8v a2h[2], a2l[2];
#pragma unroll
  for (int kf = 0; kf < 2; ++kf) {
    const float* p = &xe_s[wid][col][kf * 32 + 8 * g];
    float4v v0 = *(const float4v*)p;
    float4v v1 = *(const float4v*)(p + 4);
#pragma unroll
    for (int j = 0; j < 4; ++j) {
      short h, lo;
      f32_hilo(v0[j], h, lo); a2h[kf][j] = h;     a2l[kf][j] = lo;
      f32_hilo(v1[j], h, lo); a2h[kf][4 + j] = h; a2l[kf][4 + j] = lo;
    }
  }

  // ---- GEMM2: gate = silu(es @ W_gate), store bf16 ----
  float gate_r[8][4];
#pragma unroll
  for (int nt = 0; nt < 8; ++nt) {
    float4v a = z4;
#pragma unroll
    for (int kf = 0; kf < 2; ++kf) {
      short8v bh = *(const short8v*)(Wp2h + ((nt * 2 + kf) * 64 + lane) * 8);
      short8v bl = *(const short8v*)(Wp2l + ((nt * 2 + kf) * 64 + lane) * 8);
      a = MFMA16(a2h[kf], bh, a);
      a = MFMA16(a2h[kf], bl, a);
      a = MFMA16(a2l[kf], bh, a);
    }
#pragma unroll
    for (int r = 0; r < 4; ++r) {
      float gv = silu_f(a[r]);
      gate_r[nt][r] = gv;
      int er = e0 + 4 * g + r;
      if (er < NE)
        gate_ws[(size_t)er * 128 + nt * 16 + col] = __float2bfloat16(gv);
    }
  }

  // ---- GEMM3: msg0 = xcat @ W_msg ; epilogue: logits + segment-max ----
#pragma unroll
  for (int nt = 0; nt < 8; ++nt) {
    float4v a = z4;
#pragma unroll
    for (int kf = 0; kf < 4; ++kf) {
      short8v bh = *(const short8v*)(Wp3h + ((nt * 4 + kf) * 64 + lane) * 8);
      short8v bl = *(const short8v*)(Wp3l + ((nt * 4 + kf) * 64 + lane) * 8);
      a = MFMA16(a3h[kf], bh, a);
      a = MFMA16(a3h[kf], bl, a);
      a = MFMA16(a3l[kf], bh, a);
    }
    float al = alpha[nt * 16 + col];
#pragma unroll
    for (int r = 0; r < 4; ++r) {
      float v = a[r] * gate_r[nt][r];
      v = v > 0.0f ? v : 0.2f * v;
      v *= al;
#pragma unroll
      for (int off = 1; off < 16; off <<= 1) v += __shfl_xor(v, off);
      int er = e0 + 4 * g + r;
      if (col == 0 && er < NE) {
        logits[(size_t)er * 8 + nt] = v;
        atomicMax(&m_enc[dn_r[r] * 8 + nt], enc_f(v));
      }
    }
  }
}

// ---------------- pass2: den[n,h] += exp(logit - m[n,h])  [unchanged]
__global__ void pass2_kernel(const float* __restrict__ logits,
                             const int* __restrict__ ei,
                             const unsigned int* __restrict__ m_enc,
                             float* __restrict__ den) {
  int i = blockIdx.x * blockDim.x + threadIdx.x;
  if (i >= NE * 8) return;
  int e = i >> 3, h = i & 7;
  int dn = ei[NE + e];
  float mm = dec_f(m_enc[dn * 8 + h]);
  atomicAdd(&den[dn * 8 + h], __expf(logits[i] - mm));
}

// ---------------- pass3 (MFMA): folded message/value/force
// 16 edges/wave; barrier-free per-wave LDS; phase-D loads hoisted for MLP.
__global__ __launch_bounds__(256, 3) void pass3_kernel(
    const float* __restrict__ nb, const int* __restrict__ ei,
    const float* __restrict__ wig, const float* __restrict__ logits,
    const unsigned int* __restrict__ m_enc, const float* __restrict__ den,
    const __hip_bfloat16* __restrict__ gate_ws, const float* __restrict__ Q,
    const short* __restrict__ Wp4h, const short* __restrict__ Wp4l,
    float* __restrict__ out) {
  __shared__ __attribute__((aligned(16))) float attn_s[4][16][8];
  __shared__ __attribute__((aligned(16))) float x_s[4][16][132];  // u, then t
  const int tid = threadIdx.x;
  const int lane = tid & 63;
  const int wid = tid >> 6;
  const int g = lane >> 4;
  const int col = lane & 15;
  const int e0 = (blockIdx.x * 4 + wid) * 16;

  // preload phase-D edge indices (per 16-lane group) early
  int se_d[4], de_d[4];
#pragma unroll
  for (int it = 0; it < 4; ++it) {
    int e = it * 4 + g;
    int ec = (e0 + e < NE) ? e0 + e : NE - 1;
    se_d[it] = ei[ec];
    de_d[it] = ei[NE + ec];
  }

  // ---- phase A: attn for 16 edges x 8 heads ----
#pragma unroll
  for (int half = 0; half < 2; ++half) {
    int i = half * 64 + lane;
    int e = i >> 3, h = i & 7;
    int ec = e0 + e; if (ec >= NE) ec = NE - 1;
    int dn = ei[NE + ec];
    float l = logits[(size_t)ec * 8 + h];
    float mm = dec_f(m_enc[dn * 8 + h]);
    float dv = den[dn * 8 + h];
    attn_s[wid][e][h] = __expf(l - mm) / (dv + 1e-9f);
  }

  // ---- phase B: u[e, m] for m = 2*lane, 2*lane+1 (paired bf16 gate load) ----
  float q0[8], q1[8];
#pragma unroll
  for (int h = 0; h < 8; ++h) {
    q0[h] = Q[(2 * lane) * 8 + h];
    q1[h] = Q[(2 * lane + 1) * 8 + h];
  }
#pragma unroll 4
  for (int e = 0; e < 16; ++e) {
    int ec = e0 + e; if (ec >= NE) ec = NE - 1;
    float4v a0 = *(const float4v*)&attn_s[wid][e][0];
    float4v a1 = *(const float4v*)&attn_s[wid][e][4];
    float wv0 = 0.0f, wv1 = 0.0f;
#pragma unroll
    for (int h = 0; h < 4; ++h) {
      wv0 += q0[h] * a0[h] + q0[4 + h] * a1[h];
      wv1 += q1[h] * a0[h] + q1[4 + h] * a1[h];
    }
    unsigned int gp = *(const unsigned int*)(gate_ws + (size_t)ec * 128 + 2 * lane);
    float gg0 = __uint_as_float((gp & 0xffffu) << 16);
    float gg1 = __uint_as_float((gp & 0xffff0000u));
    float2 uu; uu.x = gg0 * wv0; uu.y = gg1 * wv1;
    *(float2*)&x_s[wid][e][2 * lane] = uu;
  }

  // ---- phase C: A-frags from u, then T = U @ Wp4 (96 MFMA), t -> x_s ----
  short8v ah[4], al[4];
#pragma unroll
  for (int kf = 0; kf < 4; ++kf) {
    const float* p = &x_s[wid][col][kf * 32 + 8 * g];
    float4v v0 = *(const float4v*)p;
    float4v v1 = *(const float4v*)(p + 4);
#pragma unroll
    for (int j = 0; j < 4; ++j) {
      short h, lo;
      f32_hilo(v0[j], h, lo); ah[kf][j] = h;     al[kf][j] = lo;
      f32_hilo(v1[j], h, lo); ah[kf][4 + j] = h; al[kf][4 + j] = lo;
    }
  }
  const float4v z4 = {0.0f, 0.0f, 0.0f, 0.0f};
#pragma unroll
  for (int nt = 0; nt < 8; ++nt) {
    float4v a = z4;
#pragma unroll
    for (int kf = 0; kf < 4; ++kf) {
      short8v bh = *(const short8v*)(Wp4h + ((nt * 4 + kf) * 64 + lane) * 8);
      short8v bl = *(const short8v*)(Wp4l + ((nt * 4 + kf) * 64 + lane) * 8);
      a = MFMA16(ah[kf], bh, a);
      a = MFMA16(ah[kf], bl, a);
      a = MFMA16(al[kf], bh, a);
    }
#pragma unroll
    for (int r = 0; r < 4; ++r)
      x_s[wid][4 * g + r][nt * 16 + col] = a[r];
  }

  // ---- phase D: d[j'] dots + wigner epilogue; 4 edges parallel (16 lanes each) ----
  const int cg = col * 4;  // 4 channels per lane
#pragma unroll
  for (int it = 0; it < 4; ++it) {
    int e = it * 4 + g;
    int eu = e0 + e;
    bool valid = eu < NE;
    int ec = valid ? eu : NE - 1;
    float4v t0 = *(const float4v*)&x_s[wid][e][cg];
    float4v t1 = *(const float4v*)&x_s[wid][e][64 + cg];
    const float* ps = nb + (size_t)se_d[it] * 576 + cg;
    const float* pt = nb + (size_t)de_d[it] * 576 + cg;
    // hoist all 18 row loads -> max MLP, single wait
    float4v pa[9], pb[9];
#pragma unroll
    for (int j = 0; j < 9; ++j) {
      pa[j] = *(const float4v*)(ps + j * 64);
      pb[j] = *(const float4v*)(pt + j * 64);
    }
    float dj[9];
#pragma unroll
    for (int j = 0; j < 9; ++j) {
      dj[j] = pa[j][0] * t0[0] + pa[j][1] * t0[1] + pa[j][2] * t0[2] + pa[j][3] * t0[3] +
              pb[j][0] * t1[0] + pb[j][1] * t1[1] + pb[j][2] * t1[2] + pb[j][3] * t1[3];
    }
#pragma unroll
    for (int j = 0; j < 9; ++j)
#pragma unroll
      for (int off = 1; off < 16; off <<= 1) dj[j] += __shfl_xor(dj[j], off);

    const float* we = wig + (size_t)ec * 81;
    int ls = col < 9 ? col : 8;
    float s_l = 0.0f;
#pragma unroll
    for (int jp = 0; jp < 9; ++jp) s_l += we[ls * 9 + jp] * dj[jp];
    int lc = (col >= 1 && col <= 3) ? col : 1;
    float f = 0.0f;
#pragma unroll
    for (int j = 0; j < 9; ++j)
      f += __shfl(s_l, (lane & 48) + j) * we[j * 9 + lc];
    if (col >= 1 && col <= 3 && valid)
      atomicAdd(&out[de_d[it] * 3 + (col - 1)], f);
  }
}

extern "C" void kernel_launch(void* const* d_in, const int* in_sizes, int n_in,
                              void* d_out, int out_size, void* d_ws, size_t ws_size,
                              hipStream_t stream) {
  const float* nb = (const float*)d_in[0];
  const int* zn = (const int*)d_in[1];
  const float* dist = (const float*)d_in[2];
  const int* ei = (const int*)d_in[3];
  const float* wig = (const float*)d_in[4];
  const float* aemb = (const float*)d_in[5];
  const float* W_rbf = (const float*)d_in[6];
  const float* W_gate = (const float*)d_in[7];
  const float* W_msg = (const float*)d_in[8];
  const float* alpha = (const float*)d_in[9];
  const float* W_val = (const float*)d_in[10];
  const float* W_out = (const float*)d_in[11];
  float* out = (float*)d_out;

  // workspace layout (~29.8 MB)
  char* p = (char*)d_ws;
  float* Q = (float*)p;                   p += 1024 * 4;
  unsigned int* m_enc = (unsigned int*)p; p += (size_t)NN * 8 * 4;
  float* den = (float*)p;                 p += (size_t)NN * 8 * 4;
  float* logits = (float*)p;              p += (size_t)NE * 8 * 4;
  __hip_bfloat16* gate_ws = (__hip_bfloat16*)p; p += (size_t)NE * 128 * 2;
  short* Wp1h = (short*)p; p += 8192 * 2;
  short* Wp1l = (short*)p; p += 8192 * 2;
  short* Wp2h = (short*)p; p += 8192 * 2;
  short* Wp2l = (short*)p; p += 8192 * 2;
  short* Wp3h = (short*)p; p += 16384 * 2;
  short* Wp3l = (short*)p; p += 16384 * 2;
  short* Wp4h = (short*)p; p += 16384 * 2;
  short* Wp4l = (short*)p; p += 16384 * 2;

  hipMemsetAsync(d_out, 0, (size_t)NN * 3 * 4, stream);
  hipMemsetAsync(m_enc, 0, (size_t)NN * 8 * 4, stream);
  hipMemsetAsync(den, 0, (size_t)NN * 8 * 4, stream);

  prep_kernel<<<192, 256, 0, stream>>>(W_msg, W_val, W_out, W_rbf, W_gate, Q,
                                       Wp1h, Wp1l, Wp2h, Wp2l, Wp3h, Wp3l, Wp4h, Wp4l);
  pass1_kernel<<<(NE + 63) / 64, 256, 0, stream>>>(nb, zn, dist, ei, wig, aemb, alpha,
                                                   Wp1h, Wp1l, Wp2h, Wp2l, Wp3h, Wp3l,
                                                   logits, m_enc, gate_ws);
  pass2_kernel<<<(NE * 8 + 255) / 256, 256, 0, stream>>>(logits, ei, m_enc, den);
  pass3_kernel<<<(NE + 63) / 64, 256, 0, stream>>>(nb, ei, wig, logits, m_enc, den,
                                                   gate_ws, Q, Wp4h, Wp4l, out);
}